// Round 1
// baseline (613.433 us; speedup 1.0000x reference)
//
#include <hip/hip_runtime.h>

#define N_NODES 50000
#define E_EDGES 800000
#define E_TOT   850000   // E + N self loops
#define IN_DIM  128
#define C1      256      // H1*HID
#define NHEAD   8
#define HID     32
#define C2      64
#define NEG     0.2f

__device__ __forceinline__ float leaky(float x){ return x > 0.f ? x : NEG * x; }
__device__ __forceinline__ float elu1(float x){ return x > 0.f ? x : __expf(x) - 1.f; }

// ---------------- CSR build ----------------
__global__ void k_count(const int* __restrict__ dst, int* __restrict__ deg){
    int e = blockIdx.x * blockDim.x + threadIdx.x;
    if (e < E_EDGES) atomicAdd(&deg[dst[e]], 1);
}

__global__ void k_scan(const int* __restrict__ deg, int* __restrict__ rowptr,
                       int* __restrict__ cursor){
    __shared__ int sdata[1024];
    const int t = threadIdx.x;
    int base = 0;
    for (int start = 0; start < N_NODES; start += 1024){
        int i = start + t;
        int v = (i < N_NODES) ? (deg[i] + 1) : 0;   // +1 for self loop
        sdata[t] = v;
        __syncthreads();
        for (int off = 1; off < 1024; off <<= 1){
            int u = (t >= off) ? sdata[t - off] : 0;
            __syncthreads();
            sdata[t] += u;
            __syncthreads();
        }
        int incl = sdata[t];
        if (i < N_NODES){
            rowptr[i] = base + incl - v;
            cursor[i] = base + incl - v;
        }
        base += sdata[1023];
        __syncthreads();
    }
    if (t == 0) rowptr[N_NODES] = base;
}

__global__ void k_scatter(const int* __restrict__ src, const int* __restrict__ dst,
                          int* __restrict__ cursor, int* __restrict__ csr){
    int e = blockIdx.x * blockDim.x + threadIdx.x;
    if (e < E_EDGES){
        int p = atomicAdd(&cursor[dst[e]], 1);
        csr[p] = src[e];
    } else if (e < E_TOT){
        int nloc = e - E_EDGES;
        int p = atomicAdd(&cursor[nloc], 1);
        csr[p] = nloc;   // self loop
    }
}

// ---------------- fp32 tiled GEMM: C[M,Nc] = A[M,K] @ B[K,Nc] ----------------
__global__ __launch_bounds__(256) void k_gemm(const float* __restrict__ A,
                                              const float* __restrict__ B,
                                              float* __restrict__ C,
                                              int M, int K, int Nc){
    __shared__ float As[32][64];   // transposed: As[k][m]
    __shared__ float Bs[32][64];
    const int t = threadIdx.x;
    const int bm0 = blockIdx.x * 64, bn0 = blockIdx.y * 64;
    const int tm = (t >> 4) << 2;
    const int tn = (t & 15) << 2;
    float acc[4][4] = {{0.f}};

    for (int kt = 0; kt < K; kt += 32){
        // A tile: 64 rows x 32 k, store transposed
        #pragma unroll
        for (int ld = 0; ld < 2; ld++){
            int r = (t >> 3) + ld * 32;
            int c = (t & 7) << 2;
            int grow = bm0 + r;
            float4 v = make_float4(0.f, 0.f, 0.f, 0.f);
            if (grow < M) v = *(const float4*)(A + (size_t)grow * K + kt + c);
            As[c    ][r] = v.x;
            As[c + 1][r] = v.y;
            As[c + 2][r] = v.z;
            As[c + 3][r] = v.w;
        }
        // B tile: 32 k x 64 n
        #pragma unroll
        for (int ld = 0; ld < 2; ld++){
            int r = (t >> 4) + ld * 16;
            int c = (t & 15) << 2;
            *(float4*)&Bs[r][c] = *(const float4*)(B + (size_t)(kt + r) * Nc + bn0 + c);
        }
        __syncthreads();
        #pragma unroll
        for (int k = 0; k < 32; k++){
            float4 a4 = *(const float4*)&As[k][tm];
            float4 b4 = *(const float4*)&Bs[k][tn];
            float av[4] = {a4.x, a4.y, a4.z, a4.w};
            float bv[4] = {b4.x, b4.y, b4.z, b4.w};
            #pragma unroll
            for (int i = 0; i < 4; i++)
                #pragma unroll
                for (int j = 0; j < 4; j++)
                    acc[i][j] += av[i] * bv[j];
        }
        __syncthreads();
    }
    #pragma unroll
    for (int i = 0; i < 4; i++){
        int grow = bm0 + tm + i;
        if (grow < M){
            float4 o = make_float4(acc[i][0], acc[i][1], acc[i][2], acc[i][3]);
            *(float4*)(C + (size_t)grow * Nc + bn0 + tn) = o;
        }
    }
}

// ---------------- conv1 attention scores: wave per node ----------------
__global__ void k_scores1(const float* __restrict__ h1, const float* __restrict__ a_src,
                          const float* __restrict__ a_dst,
                          float* __restrict__ als, float* __restrict__ ald){
    int gid = blockIdx.x * blockDim.x + threadIdx.x;
    int node = gid >> 6, lane = gid & 63;
    if (node >= N_NODES) return;
    float4 h = *(const float4*)(h1 + (size_t)node * C1 + lane * 4);
    float4 s = *(const float4*)(a_src + lane * 4);
    float4 d = *(const float4*)(a_dst + lane * 4);
    float ps = h.x * s.x + h.y * s.y + h.z * s.z + h.w * s.w;
    float pd = h.x * d.x + h.y * d.y + h.z * d.z + h.w * d.w;
    // reduce within 8-lane groups (one head each: 8 lanes * 4 feats = 32)
    #pragma unroll
    for (int off = 1; off < 8; off <<= 1){
        ps += __shfl_xor(ps, off, 64);
        pd += __shfl_xor(pd, off, 64);
    }
    if ((lane & 7) == 0){
        als[node * NHEAD + (lane >> 3)] = ps;
        ald[node * NHEAD + (lane >> 3)] = pd;
    }
}

// ---------------- conv1 online softmax stats: 8 lanes per node ----------------
__global__ void k_stats1(const int* __restrict__ rowptr, const int* __restrict__ csr,
                         const float* __restrict__ als, const float* __restrict__ ald,
                         float* __restrict__ mo, float* __restrict__ so){
    int gid = blockIdx.x * blockDim.x + threadIdx.x;
    int node = gid >> 3, h = gid & 7;
    if (node >= N_NODES) return;
    float ad = ald[node * NHEAD + h];
    int r0 = rowptr[node], r1 = rowptr[node + 1];
    float m = -1e30f, s = 0.f;
    for (int i = r0; i < r1; i++){
        int sc = csr[i];
        float e = leaky(als[sc * NHEAD + h] + ad);
        if (e > m){ s = s * __expf(m - e) + 1.f; m = e; }
        else      { s += __expf(e - m); }
    }
    mo[node * NHEAD + h] = m;
    so[node * NHEAD + h] = s;
}

// ---------------- conv1 aggregation: wave per node, lane = 4 features ----------------
__global__ __launch_bounds__(256) void k_agg1(const int* __restrict__ rowptr, const int* __restrict__ csr,
                       const float* __restrict__ h1, const float* __restrict__ als,
                       const float* __restrict__ ald, const float* __restrict__ mo,
                       const float* __restrict__ so, const float* __restrict__ b1,
                       float* __restrict__ hact){
    int gid = blockIdx.x * blockDim.x + threadIdx.x;
    int node = gid >> 6, lane = gid & 63;
    if (node >= N_NODES) return;
    int h = lane >> 3;   // feature block 4*lane -> head (4*lane)/32
    float ad   = ald[node * NHEAD + h];
    float mh   = mo[node * NHEAD + h];
    float sinv = 1.f / so[node * NHEAD + h];
    int r0 = rowptr[node], r1 = rowptr[node + 1];
    float4 acc = make_float4(0.f, 0.f, 0.f, 0.f);
    for (int i = r0; i < r1; i++){
        int sc = csr[i];
        float e = leaky(als[sc * NHEAD + h] + ad);
        float a = __expf(e - mh) * sinv;
        float4 hv = *(const float4*)(h1 + (size_t)sc * C1 + lane * 4);
        acc.x += a * hv.x; acc.y += a * hv.y; acc.z += a * hv.z; acc.w += a * hv.w;
    }
    float4 b = *(const float4*)(b1 + lane * 4);
    acc.x = elu1(acc.x + b.x);
    acc.y = elu1(acc.y + b.y);
    acc.z = elu1(acc.z + b.z);
    acc.w = elu1(acc.w + b.w);
    *(float4*)(hact + (size_t)node * C1 + lane * 4) = acc;
}

// ---------------- conv2 scores: wave per node (64 feats, 1 head) ----------------
__global__ void k_scores2(const float* __restrict__ h2, const float* __restrict__ a_src,
                          const float* __restrict__ a_dst,
                          float* __restrict__ als, float* __restrict__ ald){
    int gid = blockIdx.x * blockDim.x + threadIdx.x;
    int node = gid >> 6, lane = gid & 63;
    if (node >= N_NODES) return;
    float h = h2[(size_t)node * C2 + lane];
    float ps = h * a_src[lane];
    float pd = h * a_dst[lane];
    #pragma unroll
    for (int off = 1; off < 64; off <<= 1){
        ps += __shfl_xor(ps, off, 64);
        pd += __shfl_xor(pd, off, 64);
    }
    if (lane == 0){ als[node] = ps; ald[node] = pd; }
}

// ---------------- conv2 stats: 1 thread per node ----------------
__global__ void k_stats2(const int* __restrict__ rowptr, const int* __restrict__ csr,
                         const float* __restrict__ als, const float* __restrict__ ald,
                         float* __restrict__ mo, float* __restrict__ so){
    int node = blockIdx.x * blockDim.x + threadIdx.x;
    if (node >= N_NODES) return;
    float ad = ald[node];
    int r0 = rowptr[node], r1 = rowptr[node + 1];
    float m = -1e30f, s = 0.f;
    for (int i = r0; i < r1; i++){
        int sc = csr[i];
        float e = leaky(als[sc] + ad);
        if (e > m){ s = s * __expf(m - e) + 1.f; m = e; }
        else      { s += __expf(e - m); }
    }
    mo[node] = m;
    so[node] = s;
}

// ---------------- conv2 aggregation: wave per node, lane = 1 feature ----------------
__global__ __launch_bounds__(256) void k_agg2(const int* __restrict__ rowptr, const int* __restrict__ csr,
                       const float* __restrict__ h2, const float* __restrict__ als,
                       const float* __restrict__ ald, const float* __restrict__ mo,
                       const float* __restrict__ so, const float* __restrict__ b2,
                       float* __restrict__ out){
    int gid = blockIdx.x * blockDim.x + threadIdx.x;
    int node = gid >> 6, lane = gid & 63;
    if (node >= N_NODES) return;
    float ad   = ald[node];
    float mh   = mo[node];
    float sinv = 1.f / so[node];
    int r0 = rowptr[node], r1 = rowptr[node + 1];
    float acc = 0.f;
    for (int i = r0; i < r1; i++){
        int sc = csr[i];
        float e = leaky(als[sc] + ad);
        float a = __expf(e - mh) * sinv;
        acc += a * h2[(size_t)sc * C2 + lane];
    }
    out[(size_t)node * C2 + lane] = elu1(acc + b2[lane]);
}

extern "C" void kernel_launch(void* const* d_in, const int* in_sizes, int n_in,
                              void* d_out, int out_size, void* d_ws, size_t ws_size,
                              hipStream_t stream) {
    const float* x      = (const float*)d_in[0];
    const int*   ei     = (const int*)d_in[1];
    const float* W1     = (const float*)d_in[2];
    const float* a_src1 = (const float*)d_in[3];
    const float* a_dst1 = (const float*)d_in[4];
    const float* b1     = (const float*)d_in[5];
    const float* W2     = (const float*)d_in[6];
    const float* a_src2 = (const float*)d_in[7];
    const float* a_dst2 = (const float*)d_in[8];
    const float* b2     = (const float*)d_in[9];
    float* out = (float*)d_out;

    const int* e_src = ei;
    const int* e_dst = ei + E_EDGES;

    // ---- workspace layout (floats) ----
    float* ws = (float*)d_ws;
    float* h1   = ws;                       // N*256 = 12.8M
    float* als1 = h1 + (size_t)N_NODES * C1;
    float* ald1 = als1 + (size_t)N_NODES * NHEAD;
    float* m1   = ald1 + (size_t)N_NODES * NHEAD;
    float* s1   = m1   + (size_t)N_NODES * NHEAD;
    float* hact = s1   + (size_t)N_NODES * NHEAD;   // N*256
    float* iend = hact + (size_t)N_NODES * C1;
    int* deg    = (int*)iend;
    int* rowptr = deg + N_NODES;
    int* cursor = rowptr + N_NODES + 1;
    int* csr    = cursor + N_NODES;
    // conv2 buffers alias h1 (dead after aggregate1)
    float* h2   = h1;                        // N*64
    float* als2 = h1 + (size_t)N_NODES * C2;
    float* ald2 = als2 + N_NODES;
    float* m2   = ald2 + N_NODES;
    float* s2   = m2 + N_NODES;

    // ---- CSR build ----
    hipMemsetAsync(deg, 0, N_NODES * sizeof(int), stream);
    k_count<<<(E_EDGES + 255) / 256, 256, 0, stream>>>(e_dst, deg);
    k_scan<<<1, 1024, 0, stream>>>(deg, rowptr, cursor);
    k_scatter<<<(E_TOT + 255) / 256, 256, 0, stream>>>(e_src, e_dst, cursor, csr);

    // ---- conv1 ----
    k_gemm<<<dim3(782, 4), 256, 0, stream>>>(x, W1, h1, N_NODES, IN_DIM, C1);
    k_scores1<<<(N_NODES * 64 + 255) / 256, 256, 0, stream>>>(h1, a_src1, a_dst1, als1, ald1);
    k_stats1<<<(N_NODES * 8 + 255) / 256, 256, 0, stream>>>(rowptr, csr, als1, ald1, m1, s1);
    k_agg1<<<(N_NODES * 64 + 255) / 256, 256, 0, stream>>>(rowptr, csr, h1, als1, ald1, m1, s1, b1, hact);

    // ---- conv2 ----
    k_gemm<<<dim3(782, 1), 256, 0, stream>>>(hact, W2, h2, N_NODES, C1, C2);
    k_scores2<<<(N_NODES * 64 + 255) / 256, 256, 0, stream>>>(h2, a_src2, a_dst2, als2, ald2);
    k_stats2<<<(N_NODES + 255) / 256, 256, 0, stream>>>(rowptr, csr, als2, ald2, m2, s2);
    k_agg2<<<(N_NODES * 64 + 255) / 256, 256, 0, stream>>>(rowptr, csr, h2, als2, ald2, m2, s2, b2, out);
}

// Round 3
// 498.926 us; speedup vs baseline: 1.2295x; 1.2295x over previous
//
#include <hip/hip_runtime.h>

#define N_NODES 50000
#define E_EDGES 800000
#define E_TOT   850000   // E + N self loops
#define IN_DIM  128
#define C1      256      // H1*HID
#define NHEAD   8
#define HID     32
#define C2      64
#define NEG     0.2f
#define NBLK    196      // ceil(50000/256)

__device__ __forceinline__ float leaky(float x){ return x > 0.f ? x : NEG * x; }
__device__ __forceinline__ float elu1(float x){ return x > 0.f ? x : __expf(x) - 1.f; }

// ---------------- CSR build ----------------
__global__ void k_count(const int* __restrict__ dst, int* __restrict__ deg){
    int e = blockIdx.x * blockDim.x + threadIdx.x;
    if (e < E_EDGES) atomicAdd(&deg[dst[e]], 1);
}

// block-level exclusive scan of (deg[i]+1); writes per-block exclusive prefix + block sums
__global__ __launch_bounds__(256) void k_block_scan(const int* __restrict__ deg,
                                                    int* __restrict__ rowptr,
                                                    int* __restrict__ bsum){
    __shared__ int sd[256];
    const int t = threadIdx.x;
    int i = blockIdx.x * 256 + t;
    int v = (i < N_NODES) ? (deg[i] + 1) : 0;   // +1 for self loop
    sd[t] = v;
    __syncthreads();
    #pragma unroll
    for (int off = 1; off < 256; off <<= 1){
        int u = (t >= off) ? sd[t - off] : 0;
        __syncthreads();
        sd[t] += u;
        __syncthreads();
    }
    if (i < N_NODES) rowptr[i] = sd[t] - v;     // exclusive within block
    if (t == 255) bsum[blockIdx.x] = sd[255];
}

// scan the 196 block sums (one block); writes exclusive block offsets + total
__global__ __launch_bounds__(256) void k_scan_sums(int* __restrict__ bsum,
                                                   int* __restrict__ rowptr){
    __shared__ int sd[256];
    const int t = threadIdx.x;
    int v = (t < NBLK) ? bsum[t] : 0;
    sd[t] = v;
    __syncthreads();
    #pragma unroll
    for (int off = 1; off < 256; off <<= 1){
        int u = (t >= off) ? sd[t - off] : 0;
        __syncthreads();
        sd[t] += u;
        __syncthreads();
    }
    if (t < NBLK) bsum[t] = sd[t] - v;          // exclusive offsets (overwrite in place)
    if (t == 255) rowptr[N_NODES] = sd[255];    // total = E_TOT
}

__global__ __launch_bounds__(256) void k_add_off(const int* __restrict__ bsum,
                                                 int* __restrict__ rowptr,
                                                 int* __restrict__ cursor){
    int i = blockIdx.x * 256 + threadIdx.x;
    if (i < N_NODES){
        int r = rowptr[i] + bsum[blockIdx.x];
        rowptr[i] = r;
        cursor[i] = r;
    }
}

__global__ void k_scatter(const int* __restrict__ src, const int* __restrict__ dst,
                          int* __restrict__ cursor, int* __restrict__ csr){
    int e = blockIdx.x * blockDim.x + threadIdx.x;
    if (e < E_EDGES){
        int p = atomicAdd(&cursor[dst[e]], 1);
        if (p < E_TOT) csr[p] = src[e];
    } else if (e < E_TOT){
        int nloc = e - E_EDGES;
        int p = atomicAdd(&cursor[nloc], 1);
        if (p < E_TOT) csr[p] = nloc;   // self loop
    }
}

// ---------------- fp32 tiled GEMM: C[M,Nc] = A[M,K] @ B[K,Nc] ----------------
__global__ __launch_bounds__(256) void k_gemm(const float* __restrict__ A,
                                              const float* __restrict__ B,
                                              float* __restrict__ C,
                                              int M, int K, int Nc){
    __shared__ float As[32][64];   // transposed: As[k][m]
    __shared__ float Bs[32][64];
    const int t = threadIdx.x;
    const int bm0 = blockIdx.x * 64, bn0 = blockIdx.y * 64;
    const int tm = (t >> 4) << 2;
    const int tn = (t & 15) << 2;
    float acc[4][4] = {{0.f}};

    for (int kt = 0; kt < K; kt += 32){
        #pragma unroll
        for (int ld = 0; ld < 2; ld++){
            int r = (t >> 3) + ld * 32;
            int c = (t & 7) << 2;
            int grow = bm0 + r;
            float4 v = make_float4(0.f, 0.f, 0.f, 0.f);
            if (grow < M) v = *(const float4*)(A + (size_t)grow * K + kt + c);
            As[c    ][r] = v.x;
            As[c + 1][r] = v.y;
            As[c + 2][r] = v.z;
            As[c + 3][r] = v.w;
        }
        #pragma unroll
        for (int ld = 0; ld < 2; ld++){
            int r = (t >> 4) + ld * 16;
            int c = (t & 15) << 2;
            *(float4*)&Bs[r][c] = *(const float4*)(B + (size_t)(kt + r) * Nc + bn0 + c);
        }
        __syncthreads();
        #pragma unroll
        for (int k = 0; k < 32; k++){
            float4 a4 = *(const float4*)&As[k][tm];
            float4 b4 = *(const float4*)&Bs[k][tn];
            float av[4] = {a4.x, a4.y, a4.z, a4.w};
            float bv[4] = {b4.x, b4.y, b4.z, b4.w};
            #pragma unroll
            for (int i = 0; i < 4; i++)
                #pragma unroll
                for (int j = 0; j < 4; j++)
                    acc[i][j] += av[i] * bv[j];
        }
        __syncthreads();
    }
    #pragma unroll
    for (int i = 0; i < 4; i++){
        int grow = bm0 + tm + i;
        if (grow < M){
            float4 o = make_float4(acc[i][0], acc[i][1], acc[i][2], acc[i][3]);
            *(float4*)(C + (size_t)grow * Nc + bn0 + tn) = o;
        }
    }
}

// ---------------- conv1 attention scores: wave per node ----------------
__global__ void k_scores1(const float* __restrict__ h1, const float* __restrict__ a_src,
                          const float* __restrict__ a_dst,
                          float* __restrict__ als, float* __restrict__ ald){
    int gid = blockIdx.x * blockDim.x + threadIdx.x;
    int node = gid >> 6, lane = gid & 63;
    if (node >= N_NODES) return;
    float4 h = *(const float4*)(h1 + (size_t)node * C1 + lane * 4);
    float4 s = *(const float4*)(a_src + lane * 4);
    float4 d = *(const float4*)(a_dst + lane * 4);
    float ps = h.x * s.x + h.y * s.y + h.z * s.z + h.w * s.w;
    float pd = h.x * d.x + h.y * d.y + h.z * d.z + h.w * d.w;
    #pragma unroll
    for (int off = 1; off < 8; off <<= 1){
        ps += __shfl_xor(ps, off, 64);
        pd += __shfl_xor(pd, off, 64);
    }
    if ((lane & 7) == 0){
        als[node * NHEAD + (lane >> 3)] = ps;
        ald[node * NHEAD + (lane >> 3)] = pd;
    }
}

// ---------------- conv1 fused online-softmax aggregation: wave per node ----------------
__global__ __launch_bounds__(256) void k_agg1(const int* __restrict__ rowptr, const int* __restrict__ csr,
                       const float* __restrict__ h1, const float* __restrict__ als,
                       const float* __restrict__ ald, const float* __restrict__ b1,
                       float* __restrict__ hact){
    int gid = blockIdx.x * blockDim.x + threadIdx.x;
    int node = gid >> 6, lane = gid & 63;
    if (node >= N_NODES) return;
    int h = lane >> 3;   // feature block 4*lane -> head (4*lane)/32
    float ad = ald[node * NHEAD + h];
    int r0 = rowptr[node], r1 = rowptr[node + 1];
    float m = -1e30f, s = 0.f;
    float4 acc = make_float4(0.f, 0.f, 0.f, 0.f);
    for (int i = r0; i < r1; i++){
        int sc = csr[i];
        float e = leaky(als[sc * NHEAD + h] + ad);
        float4 hv = *(const float4*)(h1 + (size_t)sc * C1 + lane * 4);
        float mn = fmaxf(m, e);
        float r = __expf(m - mn);    // 1 when m stays
        float p = __expf(e - mn);
        s = s * r + p;
        acc.x = acc.x * r + p * hv.x;
        acc.y = acc.y * r + p * hv.y;
        acc.z = acc.z * r + p * hv.z;
        acc.w = acc.w * r + p * hv.w;
        m = mn;
    }
    float sinv = 1.f / s;
    float4 b = *(const float4*)(b1 + lane * 4);
    acc.x = elu1(acc.x * sinv + b.x);
    acc.y = elu1(acc.y * sinv + b.y);
    acc.z = elu1(acc.z * sinv + b.z);
    acc.w = elu1(acc.w * sinv + b.w);
    *(float4*)(hact + (size_t)node * C1 + lane * 4) = acc;
}

// ---------------- conv2 scores: wave per node (64 feats, 1 head) ----------------
__global__ void k_scores2(const float* __restrict__ h2, const float* __restrict__ a_src,
                          const float* __restrict__ a_dst,
                          float* __restrict__ als, float* __restrict__ ald){
    int gid = blockIdx.x * blockDim.x + threadIdx.x;
    int node = gid >> 6, lane = gid & 63;
    if (node >= N_NODES) return;
    float h = h2[(size_t)node * C2 + lane];
    float ps = h * a_src[lane];
    float pd = h * a_dst[lane];
    #pragma unroll
    for (int off = 1; off < 64; off <<= 1){
        ps += __shfl_xor(ps, off, 64);
        pd += __shfl_xor(pd, off, 64);
    }
    if (lane == 0){ als[node] = ps; ald[node] = pd; }
}

// ---------------- conv2 fused online-softmax aggregation: wave per node ----------------
__global__ __launch_bounds__(256) void k_agg2(const int* __restrict__ rowptr, const int* __restrict__ csr,
                       const float* __restrict__ h2, const float* __restrict__ als,
                       const float* __restrict__ ald, const float* __restrict__ b2,
                       float* __restrict__ out){
    int gid = blockIdx.x * blockDim.x + threadIdx.x;
    int node = gid >> 6, lane = gid & 63;
    if (node >= N_NODES) return;
    float ad = ald[node];
    int r0 = rowptr[node], r1 = rowptr[node + 1];
    float m = -1e30f, s = 0.f, acc = 0.f;
    for (int i = r0; i < r1; i++){
        int sc = csr[i];
        float e = leaky(als[sc] + ad);
        float hv = h2[(size_t)sc * C2 + lane];
        float mn = fmaxf(m, e);
        float r = __expf(m - mn);
        float p = __expf(e - mn);
        s = s * r + p;
        acc = acc * r + p * hv;
        m = mn;
    }
    out[(size_t)node * C2 + lane] = elu1(acc / s + b2[lane]);
}

extern "C" void kernel_launch(void* const* d_in, const int* in_sizes, int n_in,
                              void* d_out, int out_size, void* d_ws, size_t ws_size,
                              hipStream_t stream) {
    const float* x      = (const float*)d_in[0];
    const int*   ei     = (const int*)d_in[1];
    const float* W1     = (const float*)d_in[2];
    const float* a_src1 = (const float*)d_in[3];
    const float* a_dst1 = (const float*)d_in[4];
    const float* b1     = (const float*)d_in[5];
    const float* W2     = (const float*)d_in[6];
    const float* a_src2 = (const float*)d_in[7];
    const float* a_dst2 = (const float*)d_in[8];
    const float* b2     = (const float*)d_in[9];
    float* out = (float*)d_out;

    const int* e_src = ei;
    const int* e_dst = ei + E_EDGES;

    // ---- workspace layout (floats) ----
    float* ws = (float*)d_ws;
    float* h1   = ws;                       // N*256
    float* als1 = h1 + (size_t)N_NODES * C1;
    float* ald1 = als1 + (size_t)N_NODES * NHEAD;
    float* hact = ald1 + (size_t)N_NODES * NHEAD;   // N*256
    float* iend = hact + (size_t)N_NODES * C1;
    int* deg    = (int*)iend;
    int* rowptr = deg + N_NODES;
    int* cursor = rowptr + N_NODES + 1;
    int* bsum   = cursor + N_NODES;
    int* csr    = bsum + NBLK;
    // conv2 buffers alias h1 (dead after aggregate1)
    float* h2   = h1;                        // N*64
    float* als2 = h1 + (size_t)N_NODES * C2;
    float* ald2 = als2 + N_NODES;

    // ---- CSR build ----
    hipMemsetAsync(deg, 0, N_NODES * sizeof(int), stream);
    k_count<<<(E_EDGES + 255) / 256, 256, 0, stream>>>(e_dst, deg);
    k_block_scan<<<NBLK, 256, 0, stream>>>(deg, rowptr, bsum);
    k_scan_sums<<<1, 256, 0, stream>>>(bsum, rowptr);
    k_add_off<<<NBLK, 256, 0, stream>>>(bsum, rowptr, cursor);
    k_scatter<<<(E_TOT + 255) / 256, 256, 0, stream>>>(e_src, e_dst, cursor, csr);

    // ---- conv1 ----
    k_gemm<<<dim3(782, 4), 256, 0, stream>>>(x, W1, h1, N_NODES, IN_DIM, C1);
    k_scores1<<<(N_NODES * 64 + 255) / 256, 256, 0, stream>>>(h1, a_src1, a_dst1, als1, ald1);
    k_agg1<<<(N_NODES * 64 + 255) / 256, 256, 0, stream>>>(rowptr, csr, h1, als1, ald1, b1, hact);

    // ---- conv2 ----
    k_gemm<<<dim3(782, 1), 256, 0, stream>>>(hact, W2, h2, N_NODES, C1, C2);
    k_scores2<<<(N_NODES * 64 + 255) / 256, 256, 0, stream>>>(h2, a_src2, a_dst2, als2, ald2);
    k_agg2<<<(N_NODES * 64 + 255) / 256, 256, 0, stream>>>(rowptr, csr, h2, als2, ald2, b2, out);
}

// Round 4
// 461.362 us; speedup vs baseline: 1.3296x; 1.0814x over previous
//
#include <hip/hip_runtime.h>

#define N_NODES 50000
#define E_EDGES 800000
#define E_TOT   850000   // E + N self loops
#define IN_DIM  128
#define C1      256      // H1*HID
#define NHEAD   8
#define HID     32
#define C2      64
#define NEG     0.2f
#define NBLK    196      // ceil(50000/256)

__device__ __forceinline__ float leaky(float x){ return x > 0.f ? x : NEG * x; }
__device__ __forceinline__ float elu1(float x){ return x > 0.f ? x : __expf(x) - 1.f; }
__device__ __forceinline__ unsigned short bf16rne(float v){
    unsigned int b = __float_as_uint(v);
    b += 0x7FFFu + ((b >> 16) & 1u);
    return (unsigned short)(b >> 16);
}
__device__ __forceinline__ float bf2f(unsigned short u){
    return __uint_as_float((unsigned int)u << 16);
}

// ---------------- CSR build ----------------
__global__ void k_count(const int* __restrict__ dst, int* __restrict__ deg){
    int e = blockIdx.x * blockDim.x + threadIdx.x;
    if (e < E_EDGES) atomicAdd(&deg[dst[e]], 1);
}

__global__ __launch_bounds__(256) void k_block_scan(const int* __restrict__ deg,
                                                    int* __restrict__ rowptr,
                                                    int* __restrict__ bsum){
    __shared__ int sd[256];
    const int t = threadIdx.x;
    int i = blockIdx.x * 256 + t;
    int v = (i < N_NODES) ? (deg[i] + 1) : 0;   // +1 for self loop
    sd[t] = v;
    __syncthreads();
    #pragma unroll
    for (int off = 1; off < 256; off <<= 1){
        int u = (t >= off) ? sd[t - off] : 0;
        __syncthreads();
        sd[t] += u;
        __syncthreads();
    }
    if (i < N_NODES) rowptr[i] = sd[t] - v;     // exclusive within block
    if (t == 255) bsum[blockIdx.x] = sd[255];
}

__global__ __launch_bounds__(256) void k_scan_sums(int* __restrict__ bsum,
                                                   int* __restrict__ rowptr){
    __shared__ int sd[256];
    const int t = threadIdx.x;
    int v = (t < NBLK) ? bsum[t] : 0;
    sd[t] = v;
    __syncthreads();
    #pragma unroll
    for (int off = 1; off < 256; off <<= 1){
        int u = (t >= off) ? sd[t - off] : 0;
        __syncthreads();
        sd[t] += u;
        __syncthreads();
    }
    if (t < NBLK) bsum[t] = sd[t] - v;          // exclusive offsets
    if (t == 255) rowptr[N_NODES] = sd[255];
}

__global__ __launch_bounds__(256) void k_add_off(const int* __restrict__ bsum,
                                                 int* __restrict__ rowptr,
                                                 int* __restrict__ cursor){
    int i = blockIdx.x * 256 + threadIdx.x;
    if (i < N_NODES){
        int r = rowptr[i] + bsum[blockIdx.x];
        rowptr[i] = r;
        cursor[i] = r;
    }
}

__global__ void k_scatter(const int* __restrict__ src, const int* __restrict__ dst,
                          int* __restrict__ cursor, int* __restrict__ csr){
    int e = blockIdx.x * blockDim.x + threadIdx.x;
    if (e < E_EDGES){
        int p = atomicAdd(&cursor[dst[e]], 1);
        if (p < E_TOT) csr[p] = src[e];
    } else if (e < E_TOT){
        int nloc = e - E_EDGES;
        int p = atomicAdd(&cursor[nloc], 1);
        if (p < E_TOT) csr[p] = nloc;   // self loop
    }
}

// ---------------- GEMM1 (x@W1) with fused bf16 output + attention scores ----------------
// M=N_NODES, K=128, Nc=256. Each 64-col tile holds exactly 2 heads (32 cols each),
// so per-row head dots complete inside the block via 8-lane shuffle reduce.
__global__ __launch_bounds__(256) void k_gemm1(const float* __restrict__ A,
                                               const float* __restrict__ B,
                                               const float* __restrict__ a_src,
                                               const float* __restrict__ a_dst,
                                               unsigned short* __restrict__ h1b,
                                               float* __restrict__ als,
                                               float* __restrict__ ald){
    __shared__ float As[32][64];   // transposed: As[k][m]
    __shared__ float Bs[32][64];
    const int t = threadIdx.x;
    const int bm0 = blockIdx.x * 64, bn0 = blockIdx.y * 64;
    const int tm = (t >> 4) << 2;
    const int tn = (t & 15) << 2;
    const int cg = t & 15;
    float acc[4][4] = {{0.f}};

    for (int kt = 0; kt < IN_DIM; kt += 32){
        #pragma unroll
        for (int ld = 0; ld < 2; ld++){
            int r = (t >> 3) + ld * 32;
            int c = (t & 7) << 2;
            int grow = bm0 + r;
            float4 v = make_float4(0.f, 0.f, 0.f, 0.f);
            if (grow < N_NODES) v = *(const float4*)(A + (size_t)grow * IN_DIM + kt + c);
            As[c    ][r] = v.x;
            As[c + 1][r] = v.y;
            As[c + 2][r] = v.z;
            As[c + 3][r] = v.w;
        }
        #pragma unroll
        for (int ld = 0; ld < 2; ld++){
            int r = (t >> 4) + ld * 16;
            int c = (t & 15) << 2;
            *(float4*)&Bs[r][c] = *(const float4*)(B + (size_t)(kt + r) * C1 + bn0 + c);
        }
        __syncthreads();
        #pragma unroll
        for (int k = 0; k < 32; k++){
            float4 a4 = *(const float4*)&As[k][tm];
            float4 b4 = *(const float4*)&Bs[k][tn];
            float av[4] = {a4.x, a4.y, a4.z, a4.w};
            float bv[4] = {b4.x, b4.y, b4.z, b4.w};
            #pragma unroll
            for (int i = 0; i < 4; i++)
                #pragma unroll
                for (int j = 0; j < 4; j++)
                    acc[i][j] += av[i] * bv[j];
        }
        __syncthreads();
    }

    // epilogue: scores (fp32, exact) + bf16 feature store
    float4 as4 = *(const float4*)(a_src + bn0 + tn);
    float4 ad4 = *(const float4*)(a_dst + bn0 + tn);
    #pragma unroll
    for (int i = 0; i < 4; i++){
        float ps = acc[i][0]*as4.x + acc[i][1]*as4.y + acc[i][2]*as4.z + acc[i][3]*as4.w;
        float pd = acc[i][0]*ad4.x + acc[i][1]*ad4.y + acc[i][2]*ad4.z + acc[i][3]*ad4.w;
        #pragma unroll
        for (int off = 1; off < 8; off <<= 1){
            ps += __shfl_xor(ps, off, 64);
            pd += __shfl_xor(pd, off, 64);
        }
        int row = bm0 + tm + i;
        if (row < N_NODES){
            if ((cg & 7) == 0){
                int hd = (bn0 >> 5) + (cg >> 3);
                als[row * NHEAD + hd] = ps;
                ald[row * NHEAD + hd] = pd;
            }
            ushort4 o;
            o.x = bf16rne(acc[i][0]);
            o.y = bf16rne(acc[i][1]);
            o.z = bf16rne(acc[i][2]);
            o.w = bf16rne(acc[i][3]);
            *(ushort4*)(h1b + (size_t)row * C1 + bn0 + tn) = o;
        }
    }
}

// ---------------- generic fp32 GEMM (layer 2) ----------------
__global__ __launch_bounds__(256) void k_gemm(const float* __restrict__ A,
                                              const float* __restrict__ B,
                                              float* __restrict__ C,
                                              int M, int K, int Nc){
    __shared__ float As[32][64];
    __shared__ float Bs[32][64];
    const int t = threadIdx.x;
    const int bm0 = blockIdx.x * 64, bn0 = blockIdx.y * 64;
    const int tm = (t >> 4) << 2;
    const int tn = (t & 15) << 2;
    float acc[4][4] = {{0.f}};

    for (int kt = 0; kt < K; kt += 32){
        #pragma unroll
        for (int ld = 0; ld < 2; ld++){
            int r = (t >> 3) + ld * 32;
            int c = (t & 7) << 2;
            int grow = bm0 + r;
            float4 v = make_float4(0.f, 0.f, 0.f, 0.f);
            if (grow < M) v = *(const float4*)(A + (size_t)grow * K + kt + c);
            As[c    ][r] = v.x;
            As[c + 1][r] = v.y;
            As[c + 2][r] = v.z;
            As[c + 3][r] = v.w;
        }
        #pragma unroll
        for (int ld = 0; ld < 2; ld++){
            int r = (t >> 4) + ld * 16;
            int c = (t & 15) << 2;
            *(float4*)&Bs[r][c] = *(const float4*)(B + (size_t)(kt + r) * Nc + bn0 + c);
        }
        __syncthreads();
        #pragma unroll
        for (int k = 0; k < 32; k++){
            float4 a4 = *(const float4*)&As[k][tm];
            float4 b4 = *(const float4*)&Bs[k][tn];
            float av[4] = {a4.x, a4.y, a4.z, a4.w};
            float bv[4] = {b4.x, b4.y, b4.z, b4.w};
            #pragma unroll
            for (int i = 0; i < 4; i++)
                #pragma unroll
                for (int j = 0; j < 4; j++)
                    acc[i][j] += av[i] * bv[j];
        }
        __syncthreads();
    }
    #pragma unroll
    for (int i = 0; i < 4; i++){
        int grow = bm0 + tm + i;
        if (grow < M){
            float4 o = make_float4(acc[i][0], acc[i][1], acc[i][2], acc[i][3]);
            *(float4*)(C + (size_t)grow * Nc + bn0 + tn) = o;
        }
    }
}

// ---------------- conv1 fused online-softmax aggregation (bf16 gather) ----------------
__global__ __launch_bounds__(256) void k_agg1(const int* __restrict__ rowptr, const int* __restrict__ csr,
                       const unsigned short* __restrict__ h1b, const float* __restrict__ als,
                       const float* __restrict__ ald, const float* __restrict__ b1,
                       float* __restrict__ hact){
    int gid = blockIdx.x * blockDim.x + threadIdx.x;
    int node = gid >> 6, lane = gid & 63;
    if (node >= N_NODES) return;
    int h = lane >> 3;   // feature block 4*lane -> head (4*lane)/32
    float ad = ald[node * NHEAD + h];
    int r0 = rowptr[node], r1 = rowptr[node + 1];
    float m = -1e30f, s = 0.f;
    float4 acc = make_float4(0.f, 0.f, 0.f, 0.f);
    for (int i = r0; i < r1; i++){
        int sc = csr[i];
        float e = leaky(als[sc * NHEAD + h] + ad);
        ushort4 u = *(const ushort4*)(h1b + (size_t)sc * C1 + (lane << 2));
        float mn = fmaxf(m, e);
        float r = __expf(m - mn);    // 1 when m stays
        float p = __expf(e - mn);
        s = s * r + p;
        acc.x = acc.x * r + p * bf2f(u.x);
        acc.y = acc.y * r + p * bf2f(u.y);
        acc.z = acc.z * r + p * bf2f(u.z);
        acc.w = acc.w * r + p * bf2f(u.w);
        m = mn;
    }
    float sinv = 1.f / s;
    float4 b = *(const float4*)(b1 + (lane << 2));
    acc.x = elu1(acc.x * sinv + b.x);
    acc.y = elu1(acc.y * sinv + b.y);
    acc.z = elu1(acc.z * sinv + b.z);
    acc.w = elu1(acc.w * sinv + b.w);
    *(float4*)(hact + (size_t)node * C1 + (lane << 2)) = acc;
}

// ---------------- conv2 scores: wave per node (64 feats, 1 head) ----------------
__global__ void k_scores2(const float* __restrict__ h2, const float* __restrict__ a_src,
                          const float* __restrict__ a_dst,
                          float* __restrict__ als, float* __restrict__ ald){
    int gid = blockIdx.x * blockDim.x + threadIdx.x;
    int node = gid >> 6, lane = gid & 63;
    if (node >= N_NODES) return;
    float h = h2[(size_t)node * C2 + lane];
    float ps = h * a_src[lane];
    float pd = h * a_dst[lane];
    #pragma unroll
    for (int off = 1; off < 64; off <<= 1){
        ps += __shfl_xor(ps, off, 64);
        pd += __shfl_xor(pd, off, 64);
    }
    if (lane == 0){ als[node] = ps; ald[node] = pd; }
}

// ---------------- conv2 fused online-softmax aggregation ----------------
__global__ __launch_bounds__(256) void k_agg2(const int* __restrict__ rowptr, const int* __restrict__ csr,
                       const float* __restrict__ h2, const float* __restrict__ als,
                       const float* __restrict__ ald, const float* __restrict__ b2,
                       float* __restrict__ out){
    int gid = blockIdx.x * blockDim.x + threadIdx.x;
    int node = gid >> 6, lane = gid & 63;
    if (node >= N_NODES) return;
    float ad = ald[node];
    int r0 = rowptr[node], r1 = rowptr[node + 1];
    float m = -1e30f, s = 0.f, acc = 0.f;
    for (int i = r0; i < r1; i++){
        int sc = csr[i];
        float e = leaky(als[sc] + ad);
        float hv = h2[(size_t)sc * C2 + lane];
        float mn = fmaxf(m, e);
        float r = __expf(m - mn);
        float p = __expf(e - mn);
        s = s * r + p;
        acc = acc * r + p * hv;
        m = mn;
    }
    out[(size_t)node * C2 + lane] = elu1(acc / s + b2[lane]);
}

extern "C" void kernel_launch(void* const* d_in, const int* in_sizes, int n_in,
                              void* d_out, int out_size, void* d_ws, size_t ws_size,
                              hipStream_t stream) {
    const float* x      = (const float*)d_in[0];
    const int*   ei     = (const int*)d_in[1];
    const float* W1     = (const float*)d_in[2];
    const float* a_src1 = (const float*)d_in[3];
    const float* a_dst1 = (const float*)d_in[4];
    const float* b1     = (const float*)d_in[5];
    const float* W2     = (const float*)d_in[6];
    const float* a_src2 = (const float*)d_in[7];
    const float* a_dst2 = (const float*)d_in[8];
    const float* b2     = (const float*)d_in[9];
    float* out = (float*)d_out;

    const int* e_src = ei;
    const int* e_dst = ei + E_EDGES;

    // ---- workspace layout ----
    float* ws = (float*)d_ws;
    unsigned short* h1b = (unsigned short*)ws;            // N*256 bf16 = 6.4M floats
    float* als1 = ws + (size_t)N_NODES * C1 / 2;
    float* ald1 = als1 + (size_t)N_NODES * NHEAD;
    float* hact = ald1 + (size_t)N_NODES * NHEAD;         // N*256 fp32
    float* als2 = hact + (size_t)N_NODES * C1;
    float* ald2 = als2 + N_NODES;
    float* iend = ald2 + N_NODES;
    int* deg    = (int*)iend;
    int* rowptr = deg + N_NODES;
    int* cursor = rowptr + N_NODES + 1;
    int* bsum   = cursor + N_NODES;
    int* csr    = bsum + NBLK;
    // h2 aliases h1b region (h1b dead after agg1; needs 3.2M floats <= 6.4M)
    float* h2   = ws;

    // ---- CSR build ----
    hipMemsetAsync(deg, 0, N_NODES * sizeof(int), stream);
    k_count<<<(E_EDGES + 255) / 256, 256, 0, stream>>>(e_dst, deg);
    k_block_scan<<<NBLK, 256, 0, stream>>>(deg, rowptr, bsum);
    k_scan_sums<<<1, 256, 0, stream>>>(bsum, rowptr);
    k_add_off<<<NBLK, 256, 0, stream>>>(bsum, rowptr, cursor);
    k_scatter<<<(E_TOT + 255) / 256, 256, 0, stream>>>(e_src, e_dst, cursor, csr);

    // ---- conv1 ----
    k_gemm1<<<dim3(782, 4), 256, 0, stream>>>(x, W1, a_src1, a_dst1, h1b, als1, ald1);
    k_agg1<<<(N_NODES * 64 + 255) / 256, 256, 0, stream>>>(rowptr, csr, h1b, als1, ald1, b1, hact);

    // ---- conv2 ----
    k_gemm<<<dim3(782, 1), 256, 0, stream>>>(hact, W2, h2, N_NODES, C1, C2);
    k_scores2<<<(N_NODES * 64 + 255) / 256, 256, 0, stream>>>(h2, a_src2, a_dst2, als2, ald2);
    k_agg2<<<(N_NODES * 64 + 255) / 256, 256, 0, stream>>>(rowptr, csr, h2, als2, ald2, b2, out);
}

// Round 5
// 378.534 us; speedup vs baseline: 1.6206x; 1.2188x over previous
//
#include <hip/hip_runtime.h>

#define N_NODES 50000
#define E_EDGES 800000
#define E_TOT   850000   // E + N self loops
#define IN_DIM  128
#define C1      256      // H1*HID
#define NHEAD   8
#define HID     32
#define C2      64
#define NEG     0.2f
#define NBLK    196      // ceil(50000/256)

__device__ __forceinline__ float leaky(float x){ return x > 0.f ? x : NEG * x; }
__device__ __forceinline__ float elu1(float x){ return x > 0.f ? x : __expf(x) - 1.f; }
__device__ __forceinline__ unsigned short bf16rne(float v){
    unsigned int b = __float_as_uint(v);
    b += 0x7FFFu + ((b >> 16) & 1u);
    return (unsigned short)(b >> 16);
}
__device__ __forceinline__ float bf2f(unsigned short u){
    return __uint_as_float((unsigned int)u << 16);
}

// ---------------- CSR build ----------------
__global__ void k_count(const int* __restrict__ dst, int* __restrict__ deg){
    int e = blockIdx.x * blockDim.x + threadIdx.x;
    if (e < E_EDGES) atomicAdd(&deg[dst[e]], 1);
}

__global__ __launch_bounds__(256) void k_block_scan(const int* __restrict__ deg,
                                                    int* __restrict__ rowptr,
                                                    int* __restrict__ bsum){
    __shared__ int sd[256];
    const int t = threadIdx.x;
    int i = blockIdx.x * 256 + t;
    int v = (i < N_NODES) ? (deg[i] + 1) : 0;   // +1 for self loop
    sd[t] = v;
    __syncthreads();
    #pragma unroll
    for (int off = 1; off < 256; off <<= 1){
        int u = (t >= off) ? sd[t - off] : 0;
        __syncthreads();
        sd[t] += u;
        __syncthreads();
    }
    if (i < N_NODES) rowptr[i] = sd[t] - v;     // exclusive within block
    if (t == 255) bsum[blockIdx.x] = sd[255];
}

__global__ __launch_bounds__(256) void k_scan_sums(int* __restrict__ bsum,
                                                   int* __restrict__ rowptr){
    __shared__ int sd[256];
    const int t = threadIdx.x;
    int v = (t < NBLK) ? bsum[t] : 0;
    sd[t] = v;
    __syncthreads();
    #pragma unroll
    for (int off = 1; off < 256; off <<= 1){
        int u = (t >= off) ? sd[t - off] : 0;
        __syncthreads();
        sd[t] += u;
        __syncthreads();
    }
    if (t < NBLK) bsum[t] = sd[t] - v;          // exclusive offsets
    if (t == 255) rowptr[N_NODES] = sd[255];
}

__global__ __launch_bounds__(256) void k_add_off(const int* __restrict__ bsum,
                                                 int* __restrict__ rowptr,
                                                 int* __restrict__ cursor){
    int i = blockIdx.x * 256 + threadIdx.x;
    if (i < N_NODES){
        int r = rowptr[i] + bsum[blockIdx.x];
        rowptr[i] = r;
        cursor[i] = r;
    }
}

__global__ void k_scatter(const int* __restrict__ src, const int* __restrict__ dst,
                          int* __restrict__ cursor, int* __restrict__ csr){
    int e = blockIdx.x * blockDim.x + threadIdx.x;
    if (e < E_EDGES){
        int p = atomicAdd(&cursor[dst[e]], 1);
        if (p < E_TOT) csr[p] = src[e];
    } else if (e < E_TOT){
        int nloc = e - E_EDGES;
        int p = atomicAdd(&cursor[nloc], 1);
        if (p < E_TOT) csr[p] = nloc;   // self loop
    }
}

// ---------------- GEMM1 (x@W1) with fused bf16 output + attention scores ----------------
__global__ __launch_bounds__(256) void k_gemm1(const float* __restrict__ A,
                                               const float* __restrict__ B,
                                               const float* __restrict__ a_src,
                                               const float* __restrict__ a_dst,
                                               unsigned short* __restrict__ h1b,
                                               float* __restrict__ als,
                                               float* __restrict__ ald){
    __shared__ float As[32][64];   // transposed: As[k][m]
    __shared__ float Bs[32][64];
    const int t = threadIdx.x;
    const int bm0 = blockIdx.x * 64, bn0 = blockIdx.y * 64;
    const int tm = (t >> 4) << 2;
    const int tn = (t & 15) << 2;
    const int cg = t & 15;
    float acc[4][4] = {{0.f}};

    for (int kt = 0; kt < IN_DIM; kt += 32){
        #pragma unroll
        for (int ld = 0; ld < 2; ld++){
            int r = (t >> 3) + ld * 32;
            int c = (t & 7) << 2;
            int grow = bm0 + r;
            float4 v = make_float4(0.f, 0.f, 0.f, 0.f);
            if (grow < N_NODES) v = *(const float4*)(A + (size_t)grow * IN_DIM + kt + c);
            As[c    ][r] = v.x;
            As[c + 1][r] = v.y;
            As[c + 2][r] = v.z;
            As[c + 3][r] = v.w;
        }
        #pragma unroll
        for (int ld = 0; ld < 2; ld++){
            int r = (t >> 4) + ld * 16;
            int c = (t & 15) << 2;
            *(float4*)&Bs[r][c] = *(const float4*)(B + (size_t)(kt + r) * C1 + bn0 + c);
        }
        __syncthreads();
        #pragma unroll
        for (int k = 0; k < 32; k++){
            float4 a4 = *(const float4*)&As[k][tm];
            float4 b4 = *(const float4*)&Bs[k][tn];
            float av[4] = {a4.x, a4.y, a4.z, a4.w};
            float bv[4] = {b4.x, b4.y, b4.z, b4.w};
            #pragma unroll
            for (int i = 0; i < 4; i++)
                #pragma unroll
                for (int j = 0; j < 4; j++)
                    acc[i][j] += av[i] * bv[j];
        }
        __syncthreads();
    }

    float4 as4 = *(const float4*)(a_src + bn0 + tn);
    float4 ad4 = *(const float4*)(a_dst + bn0 + tn);
    #pragma unroll
    for (int i = 0; i < 4; i++){
        float ps = acc[i][0]*as4.x + acc[i][1]*as4.y + acc[i][2]*as4.z + acc[i][3]*as4.w;
        float pd = acc[i][0]*ad4.x + acc[i][1]*ad4.y + acc[i][2]*ad4.z + acc[i][3]*ad4.w;
        #pragma unroll
        for (int off = 1; off < 8; off <<= 1){
            ps += __shfl_xor(ps, off, 64);
            pd += __shfl_xor(pd, off, 64);
        }
        int row = bm0 + tm + i;
        if (row < N_NODES){
            if ((cg & 7) == 0){
                int hd = (bn0 >> 5) + (cg >> 3);
                als[row * NHEAD + hd] = ps;
                ald[row * NHEAD + hd] = pd;
            }
            ushort4 o;
            o.x = bf16rne(acc[i][0]);
            o.y = bf16rne(acc[i][1]);
            o.z = bf16rne(acc[i][2]);
            o.w = bf16rne(acc[i][3]);
            *(ushort4*)(h1b + (size_t)row * C1 + bn0 + tn) = o;
        }
    }
}

// ---------------- GEMM2 (hact@W2) with fused conv2 attention scores ----------------
// M=N_NODES, K=256, Nc=64 (single col-tile). Row dot over all 64 cols ->
// reduce across the 16 lanes holding the row (shfl_xor 1,2,4,8).
__global__ __launch_bounds__(256) void k_gemm2(const float* __restrict__ A,
                                               const float* __restrict__ B,
                                               const float* __restrict__ a_src,
                                               const float* __restrict__ a_dst,
                                               float* __restrict__ C,
                                               float* __restrict__ als,
                                               float* __restrict__ ald){
    __shared__ float As[32][64];
    __shared__ float Bs[32][64];
    const int t = threadIdx.x;
    const int bm0 = blockIdx.x * 64;
    const int tm = (t >> 4) << 2;
    const int tn = (t & 15) << 2;
    float acc[4][4] = {{0.f}};

    for (int kt = 0; kt < C1; kt += 32){
        #pragma unroll
        for (int ld = 0; ld < 2; ld++){
            int r = (t >> 3) + ld * 32;
            int c = (t & 7) << 2;
            int grow = bm0 + r;
            float4 v = make_float4(0.f, 0.f, 0.f, 0.f);
            if (grow < N_NODES) v = *(const float4*)(A + (size_t)grow * C1 + kt + c);
            As[c    ][r] = v.x;
            As[c + 1][r] = v.y;
            As[c + 2][r] = v.z;
            As[c + 3][r] = v.w;
        }
        #pragma unroll
        for (int ld = 0; ld < 2; ld++){
            int r = (t >> 4) + ld * 16;
            int c = (t & 15) << 2;
            *(float4*)&Bs[r][c] = *(const float4*)(B + (size_t)(kt + r) * C2 + c);
        }
        __syncthreads();
        #pragma unroll
        for (int k = 0; k < 32; k++){
            float4 a4 = *(const float4*)&As[k][tm];
            float4 b4 = *(const float4*)&Bs[k][tn];
            float av[4] = {a4.x, a4.y, a4.z, a4.w};
            float bv[4] = {b4.x, b4.y, b4.z, b4.w};
            #pragma unroll
            for (int i = 0; i < 4; i++)
                #pragma unroll
                for (int j = 0; j < 4; j++)
                    acc[i][j] += av[i] * bv[j];
        }
        __syncthreads();
    }

    float4 as4 = *(const float4*)(a_src + tn);
    float4 ad4 = *(const float4*)(a_dst + tn);
    #pragma unroll
    for (int i = 0; i < 4; i++){
        float ps = acc[i][0]*as4.x + acc[i][1]*as4.y + acc[i][2]*as4.z + acc[i][3]*as4.w;
        float pd = acc[i][0]*ad4.x + acc[i][1]*ad4.y + acc[i][2]*ad4.z + acc[i][3]*ad4.w;
        #pragma unroll
        for (int off = 1; off < 16; off <<= 1){
            ps += __shfl_xor(ps, off, 64);
            pd += __shfl_xor(pd, off, 64);
        }
        int row = bm0 + tm + i;
        if (row < N_NODES){
            if ((t & 15) == 0){
                als[row] = ps;
                ald[row] = pd;
            }
            float4 o = make_float4(acc[i][0], acc[i][1], acc[i][2], acc[i][3]);
            *(float4*)(C + (size_t)row * C2 + tn) = o;
        }
    }
}

// ---------------- conv1 fused online-softmax aggregation (bf16 gather, 4x MLP) ----------------
__global__ __launch_bounds__(256) void k_agg1(const int* __restrict__ rowptr, const int* __restrict__ csr,
                       const unsigned short* __restrict__ h1b, const float* __restrict__ als,
                       const float* __restrict__ ald, const float* __restrict__ b1,
                       float* __restrict__ hact){
    int gid = blockIdx.x * blockDim.x + threadIdx.x;
    int node = gid >> 6, lane = gid & 63;
    if (node >= N_NODES) return;
    int h = lane >> 3;
    float ad = ald[node * NHEAD + h];
    int r0 = rowptr[node], r1 = rowptr[node + 1];
    float m = -1e30f, s = 0.f;
    float4 acc = make_float4(0.f, 0.f, 0.f, 0.f);
    int i = r0;
    for (; i + 3 < r1; i += 4){
        int sc0 = csr[i], sc1 = csr[i+1], sc2 = csr[i+2], sc3 = csr[i+3];
        float e0 = leaky(als[sc0 * NHEAD + h] + ad);
        float e1 = leaky(als[sc1 * NHEAD + h] + ad);
        float e2 = leaky(als[sc2 * NHEAD + h] + ad);
        float e3 = leaky(als[sc3 * NHEAD + h] + ad);
        ushort4 u0 = *(const ushort4*)(h1b + (size_t)sc0 * C1 + (lane << 2));
        ushort4 u1 = *(const ushort4*)(h1b + (size_t)sc1 * C1 + (lane << 2));
        ushort4 u2 = *(const ushort4*)(h1b + (size_t)sc2 * C1 + (lane << 2));
        ushort4 u3 = *(const ushort4*)(h1b + (size_t)sc3 * C1 + (lane << 2));
        float mn = fmaxf(m, fmaxf(fmaxf(e0, e1), fmaxf(e2, e3)));
        float r  = __expf(m - mn);
        float p0 = __expf(e0 - mn), p1 = __expf(e1 - mn);
        float p2 = __expf(e2 - mn), p3 = __expf(e3 - mn);
        s = s * r + ((p0 + p1) + (p2 + p3));
        acc.x = acc.x * r + (p0*bf2f(u0.x) + p1*bf2f(u1.x) + p2*bf2f(u2.x) + p3*bf2f(u3.x));
        acc.y = acc.y * r + (p0*bf2f(u0.y) + p1*bf2f(u1.y) + p2*bf2f(u2.y) + p3*bf2f(u3.y));
        acc.z = acc.z * r + (p0*bf2f(u0.z) + p1*bf2f(u1.z) + p2*bf2f(u2.z) + p3*bf2f(u3.z));
        acc.w = acc.w * r + (p0*bf2f(u0.w) + p1*bf2f(u1.w) + p2*bf2f(u2.w) + p3*bf2f(u3.w));
        m = mn;
    }
    for (; i < r1; i++){
        int sc = csr[i];
        float e = leaky(als[sc * NHEAD + h] + ad);
        ushort4 u = *(const ushort4*)(h1b + (size_t)sc * C1 + (lane << 2));
        float mn = fmaxf(m, e);
        float r = __expf(m - mn);
        float p = __expf(e - mn);
        s = s * r + p;
        acc.x = acc.x * r + p * bf2f(u.x);
        acc.y = acc.y * r + p * bf2f(u.y);
        acc.z = acc.z * r + p * bf2f(u.z);
        acc.w = acc.w * r + p * bf2f(u.w);
        m = mn;
    }
    float sinv = 1.f / s;
    float4 b = *(const float4*)(b1 + (lane << 2));
    acc.x = elu1(acc.x * sinv + b.x);
    acc.y = elu1(acc.y * sinv + b.y);
    acc.z = elu1(acc.z * sinv + b.z);
    acc.w = elu1(acc.w * sinv + b.w);
    *(float4*)(hact + (size_t)node * C1 + (lane << 2)) = acc;
}

// ---------------- conv2 fused online-softmax aggregation (4x MLP) ----------------
__global__ __launch_bounds__(256) void k_agg2(const int* __restrict__ rowptr, const int* __restrict__ csr,
                       const float* __restrict__ h2, const float* __restrict__ als,
                       const float* __restrict__ ald, const float* __restrict__ b2,
                       float* __restrict__ out){
    int gid = blockIdx.x * blockDim.x + threadIdx.x;
    int node = gid >> 6, lane = gid & 63;
    if (node >= N_NODES) return;
    float ad = ald[node];
    int r0 = rowptr[node], r1 = rowptr[node + 1];
    float m = -1e30f, s = 0.f, acc = 0.f;
    int i = r0;
    for (; i + 3 < r1; i += 4){
        int sc0 = csr[i], sc1 = csr[i+1], sc2 = csr[i+2], sc3 = csr[i+3];
        float e0 = leaky(als[sc0] + ad);
        float e1 = leaky(als[sc1] + ad);
        float e2 = leaky(als[sc2] + ad);
        float e3 = leaky(als[sc3] + ad);
        float f0 = h2[(size_t)sc0 * C2 + lane];
        float f1 = h2[(size_t)sc1 * C2 + lane];
        float f2 = h2[(size_t)sc2 * C2 + lane];
        float f3 = h2[(size_t)sc3 * C2 + lane];
        float mn = fmaxf(m, fmaxf(fmaxf(e0, e1), fmaxf(e2, e3)));
        float r  = __expf(m - mn);
        float p0 = __expf(e0 - mn), p1 = __expf(e1 - mn);
        float p2 = __expf(e2 - mn), p3 = __expf(e3 - mn);
        s = s * r + ((p0 + p1) + (p2 + p3));
        acc = acc * r + (p0*f0 + p1*f1 + p2*f2 + p3*f3);
        m = mn;
    }
    for (; i < r1; i++){
        int sc = csr[i];
        float e = leaky(als[sc] + ad);
        float hv = h2[(size_t)sc * C2 + lane];
        float mn = fmaxf(m, e);
        float r = __expf(m - mn);
        float p = __expf(e - mn);
        s = s * r + p;
        acc = acc * r + p * hv;
        m = mn;
    }
    out[(size_t)node * C2 + lane] = elu1(acc / s + b2[lane]);
}

extern "C" void kernel_launch(void* const* d_in, const int* in_sizes, int n_in,
                              void* d_out, int out_size, void* d_ws, size_t ws_size,
                              hipStream_t stream) {
    const float* x      = (const float*)d_in[0];
    const int*   ei     = (const int*)d_in[1];
    const float* W1     = (const float*)d_in[2];
    const float* a_src1 = (const float*)d_in[3];
    const float* a_dst1 = (const float*)d_in[4];
    const float* b1     = (const float*)d_in[5];
    const float* W2     = (const float*)d_in[6];
    const float* a_src2 = (const float*)d_in[7];
    const float* a_dst2 = (const float*)d_in[8];
    const float* b2     = (const float*)d_in[9];
    float* out = (float*)d_out;

    const int* e_src = ei;
    const int* e_dst = ei + E_EDGES;

    // ---- workspace layout ----
    float* ws = (float*)d_ws;
    unsigned short* h1b = (unsigned short*)ws;            // N*256 bf16
    float* als1 = ws + (size_t)N_NODES * C1 / 2;
    float* ald1 = als1 + (size_t)N_NODES * NHEAD;
    float* hact = ald1 + (size_t)N_NODES * NHEAD;         // N*256 fp32
    float* als2 = hact + (size_t)N_NODES * C1;
    float* ald2 = als2 + N_NODES;
    float* iend = ald2 + N_NODES;
    int* deg    = (int*)iend;
    int* rowptr = deg + N_NODES;
    int* cursor = rowptr + N_NODES + 1;
    int* bsum   = cursor + N_NODES;
    int* csr    = bsum + NBLK;
    // h2 aliases h1b region (h1b dead after agg1)
    float* h2   = ws;

    // ---- CSR build ----
    hipMemsetAsync(deg, 0, N_NODES * sizeof(int), stream);
    k_count<<<(E_EDGES + 255) / 256, 256, 0, stream>>>(e_dst, deg);
    k_block_scan<<<NBLK, 256, 0, stream>>>(deg, rowptr, bsum);
    k_scan_sums<<<1, 256, 0, stream>>>(bsum, rowptr);
    k_add_off<<<NBLK, 256, 0, stream>>>(bsum, rowptr, cursor);
    k_scatter<<<(E_TOT + 255) / 256, 256, 0, stream>>>(e_src, e_dst, cursor, csr);

    // ---- conv1 ----
    k_gemm1<<<dim3(782, 4), 256, 0, stream>>>(x, W1, a_src1, a_dst1, h1b, als1, ald1);
    k_agg1<<<(N_NODES * 64 + 255) / 256, 256, 0, stream>>>(rowptr, csr, h1b, als1, ald1, b1, hact);

    // ---- conv2 ----
    k_gemm2<<<dim3(782, 1), 256, 0, stream>>>(hact, W2, a_src2, a_dst2, h2, als2, ald2);
    k_agg2<<<(N_NODES * 64 + 255) / 256, 256, 0, stream>>>(rowptr, csr, h2, als2, ald2, b2, out);
}